// Round 4
// baseline (383.056 us; speedup 1.0000x reference)
//
#include <hip/hip_runtime.h>
#include <cstdint>
#include <cstddef>

#define N_NODES 50000
#define N_EDGES 800000
#define F_IN    128
#define F_HID   256
#define F_OUT   40
#define NB      196     // ceil(N_NODES / 256)
#define NCOPY   8       // one histogram/cursor replica per XCD
#define SREP    50176   // replica stride (>= N_NODES, 256-aligned)

// ---------------------------------------------------------------------------
// Pass 1: degree histogram, 8-way replicated by blockIdx&7 (~XCD id).
// Atomics stay in the local XCD's L2 -> no cross-XCD line ping-pong.
// ---------------------------------------------------------------------------
__global__ __launch_bounds__(256) void degree_kernel(
    const int* __restrict__ src, const int* __restrict__ dst,
    int* __restrict__ degc_out, int* __restrict__ degc_in) {
  int b = blockIdx.x;
  int i = b * 256 + threadIdx.x;
  int k = b & (NCOPY - 1);
  if (i < N_EDGES) {
    atomicAdd(&degc_out[k * SREP + src[i]], 1);
    atomicAdd(&degc_in[k * SREP + dst[i]], 1);
  }
}

// ---------------------------------------------------------------------------
// Pass 2: reduce replicas -> total in-degree + both norms
// ---------------------------------------------------------------------------
__global__ __launch_bounds__(256) void reduce_kernel(
    const int* __restrict__ degc_out, const int* __restrict__ degc_in,
    int* __restrict__ deg_in_tot, float* __restrict__ norm_src,
    float* __restrict__ norm_dst) {
  int v = blockIdx.x * 256 + threadIdx.x;
  if (v >= N_NODES) return;
  int di = 0, dq = 0;
#pragma unroll
  for (int k = 0; k < NCOPY; ++k) {
    di += degc_in[k * SREP + v];
    dq += degc_out[k * SREP + v];
  }
  deg_in_tot[v] = di;
  norm_dst[v] = 1.0f / sqrtf(fmaxf((float)di, 1.0f));
  norm_src[v] = 1.0f / sqrtf(fmaxf((float)dq, 1.0f));
}

// ---------------------------------------------------------------------------
// Pass 3a: per-block (256-node chunk) sums of in-degree
// ---------------------------------------------------------------------------
__global__ __launch_bounds__(256) void block_sum_kernel(
    const int* __restrict__ deg_in, int* __restrict__ bsum) {
  __shared__ int arr[256];
  int node = blockIdx.x * 256 + threadIdx.x;
  arr[threadIdx.x] = (node < N_NODES) ? deg_in[node] : 0;
  __syncthreads();
  for (int off = 128; off > 0; off >>= 1) {
    if (threadIdx.x < off) arr[threadIdx.x] += arr[threadIdx.x + off];
    __syncthreads();
  }
  if (threadIdx.x == 0) bsum[blockIdx.x] = arr[0];
}

// ---------------------------------------------------------------------------
// Pass 3b: exclusive scan of the NB block sums (single small block)
// ---------------------------------------------------------------------------
__global__ __launch_bounds__(256) void scan_bsum_kernel(int* __restrict__ bsum) {
  __shared__ int arr[256];
  int tid = threadIdx.x;
  int v = (tid < NB) ? bsum[tid] : 0;
  arr[tid] = v;
  __syncthreads();
  for (int off = 1; off < 256; off <<= 1) {
    int t = (tid >= off) ? arr[tid - off] : 0;
    __syncthreads();
    arr[tid] += t;
    __syncthreads();
  }
  if (tid < NB) bsum[tid] = arr[tid] - v;  // exclusive
}

// ---------------------------------------------------------------------------
// Pass 3c: finalize — row_ptr + per-replica cursor bases
// cur[k][v] = row_ptr[v] + sum_{j<k} degc_in[j][v]
// ---------------------------------------------------------------------------
__global__ __launch_bounds__(256) void finalize_kernel(
    const int* __restrict__ deg_in_tot, const int* __restrict__ degc_in,
    const int* __restrict__ bsum, int* __restrict__ row_ptr,
    int* __restrict__ cur) {
  __shared__ int arr[256];
  int tid = threadIdx.x;
  int node = blockIdx.x * 256 + tid;
  int di = (node < N_NODES) ? deg_in_tot[node] : 0;
  arr[tid] = di;
  __syncthreads();
  for (int off = 1; off < 256; off <<= 1) {
    int t = (tid >= off) ? arr[tid - off] : 0;
    __syncthreads();
    arr[tid] += t;
    __syncthreads();
  }
  if (node < N_NODES) {
    int rp = bsum[blockIdx.x] + arr[tid] - di;  // exclusive prefix
    row_ptr[node] = rp;
    int b = rp;
#pragma unroll
    for (int k = 0; k < NCOPY; ++k) {
      cur[k * SREP + node] = b;
      b += degc_in[k * SREP + node];
    }
  }
  if (blockIdx.x == 0 && tid == 0) row_ptr[N_NODES] = N_EDGES;
}

// ---------------------------------------------------------------------------
// Pass 4: scatter edges into CSR buckets via the replica cursor.
// Same grid & copy mapping as degree_kernel -> per-copy counts match exactly.
// ---------------------------------------------------------------------------
__global__ __launch_bounds__(256) void scatter_kernel(
    const int* __restrict__ src, const int* __restrict__ dst,
    int* __restrict__ cur, int* __restrict__ csr_src) {
  int b = blockIdx.x;
  int i = b * 256 + threadIdx.x;
  int k = b & (NCOPY - 1);
  if (i < N_EDGES) {
    int d = dst[i];
    int p = atomicAdd(&cur[k * SREP + d], 1);
    csr_src[p] = src[i];
  }
}

// ---------------------------------------------------------------------------
// Pass 5: xs = feat * norm_src[row]
// ---------------------------------------------------------------------------
__global__ __launch_bounds__(256) void prescale_kernel(
    const float* __restrict__ feat, const float* __restrict__ norm_src,
    float* __restrict__ xs) {
  int i = blockIdx.x * 256 + threadIdx.x;  // one float4 per thread, exact grid
  int row = i >> 5;                        // 32 float4 per row
  float4 v = ((const float4*)feat)[i];
  float ns = norm_src[row];
  v.x *= ns; v.y *= ns; v.z *= ns; v.w *= ns;
  ((float4*)xs)[i] = v;
}

// ---------------------------------------------------------------------------
// Pass 6: layer-1 aggregation at dim 128. One wave per dst node, 2 edges in
// flight (two 32-lane float4 groups), index prefetch.
// ---------------------------------------------------------------------------
__global__ __launch_bounds__(256) void agg1_kernel(
    const float* __restrict__ xs, const int* __restrict__ row_ptr,
    const int* __restrict__ csr_src, const float* __restrict__ norm_dst,
    float* __restrict__ out) {
  int wid = (blockIdx.x * 256 + threadIdx.x) >> 6;
  if (wid >= N_NODES) return;
  int lane = threadIdx.x & 63;
  int g = lane >> 5;
  int l32 = lane & 31;
  int beg = row_ptr[wid], end = row_ptr[wid + 1];
  float4 acc = make_float4(0.f, 0.f, 0.f, 0.f);
  int e = beg + g;
  if (e < end) {
    int s = csr_src[e];
    while (true) {
      int en = e + 2;
      int sn = (en < end) ? csr_src[en] : 0;
      float4 f = *(const float4*)(xs + (size_t)s * F_IN + (l32 << 2));
      acc.x += f.x; acc.y += f.y; acc.z += f.z; acc.w += f.w;
      if (en >= end) break;
      e = en; s = sn;
    }
  }
  acc.x += __shfl_xor(acc.x, 32);
  acc.y += __shfl_xor(acc.y, 32);
  acc.z += __shfl_xor(acc.z, 32);
  acc.w += __shfl_xor(acc.w, 32);
  if (g == 0) {
    float nd = norm_dst[wid];
    acc.x *= nd; acc.y *= nd; acc.z *= nd; acc.w *= nd;
    *(float4*)(out + (size_t)wid * F_IN + (l32 << 2)) = acc;
  }
}

// ---------------------------------------------------------------------------
// fp32 GEMM, layer 1: h = relu(agg1 @ W1 + b1). 128x64x32, TM=8 TN=4.
// ---------------------------------------------------------------------------
__global__ __launch_bounds__(256) void gemm1_kernel(
    const float* __restrict__ A, const float* __restrict__ B,
    const float* __restrict__ bias, float* __restrict__ C, int M) {
  constexpr int BM = 128, BN = 64, BK = 32, TM = 8, TN = 4;
  constexpr int N = F_HID, K = F_IN;
  __shared__ float As[BK][BM + 4];
  __shared__ float Bs[BK][BN];
  int tid = threadIdx.x;
  int tx = tid % (BN / TN);
  int ty = tid / (BN / TN);
  int row0 = blockIdx.x * BM;
  int col0 = blockIdx.y * BN;
  float acc[TM][TN];
#pragma unroll
  for (int i = 0; i < TM; ++i)
#pragma unroll
    for (int j = 0; j < TN; ++j) acc[i][j] = 0.f;

  for (int k0 = 0; k0 < K; k0 += BK) {
#pragma unroll
    for (int idx = tid; idx < BM * BK / 4; idx += 256) {
      int r = idx / (BK / 4);
      int c4 = idx % (BK / 4);
      int row = row0 + r;
      float4 v = (row < M) ? *(const float4*)(A + (size_t)row * K + k0 + c4 * 4)
                           : make_float4(0.f, 0.f, 0.f, 0.f);
      As[c4 * 4 + 0][r] = v.x;
      As[c4 * 4 + 1][r] = v.y;
      As[c4 * 4 + 2][r] = v.z;
      As[c4 * 4 + 3][r] = v.w;
    }
#pragma unroll
    for (int idx = tid; idx < BK * BN / 4; idx += 256) {
      int r = idx / (BN / 4);
      int c4 = idx % (BN / 4);
      *(float4*)(&Bs[r][c4 * 4]) =
          *(const float4*)(B + (size_t)(k0 + r) * N + col0 + c4 * 4);
    }
    __syncthreads();
#pragma unroll
    for (int k = 0; k < BK; ++k) {
      float4 a0 = *(const float4*)(&As[k][ty * TM]);
      float4 a1 = *(const float4*)(&As[k][ty * TM + 4]);
      float4 b0 = *(const float4*)(&Bs[k][tx * TN]);
      float a[TM] = {a0.x, a0.y, a0.z, a0.w, a1.x, a1.y, a1.z, a1.w};
      float b[TN] = {b0.x, b0.y, b0.z, b0.w};
#pragma unroll
      for (int i = 0; i < TM; ++i)
#pragma unroll
        for (int j = 0; j < TN; ++j) acc[i][j] += a[i] * b[j];
    }
    __syncthreads();
  }

#pragma unroll
  for (int i = 0; i < TM; ++i) {
    int row = row0 + ty * TM + i;
    if (row >= M) continue;
    float4 bv = *(const float4*)(bias + col0 + tx * TN);
    float4 v = make_float4(fmaxf(acc[i][0] + bv.x, 0.f),
                           fmaxf(acc[i][1] + bv.y, 0.f),
                           fmaxf(acc[i][2] + bv.z, 0.f),
                           fmaxf(acc[i][3] + bv.w, 0.f));
    *(float4*)(C + (size_t)row * N + col0 + tx * TN) = v;
  }
}

// ---------------------------------------------------------------------------
// fp32 GEMM, layer 2: t = (h @ W2) * norm_src[row]. 128x40x32, 320 threads.
// ---------------------------------------------------------------------------
__global__ __launch_bounds__(320) void gemm2_kernel(
    const float* __restrict__ A, const float* __restrict__ B,
    const float* __restrict__ rowscale, float* __restrict__ C, int M) {
  constexpr int BM = 128, BN = 40, BK = 32, TM = 4, TN = 4;
  constexpr int N = F_OUT, K = F_HID;
  __shared__ float As[BK][BM + 4];
  __shared__ float Bs[BK][BN];
  int tid = threadIdx.x;
  int tx = tid % (BN / TN);
  int ty = tid / (BN / TN);
  int row0 = blockIdx.x * BM;
  float acc[TM][TN];
#pragma unroll
  for (int i = 0; i < TM; ++i)
#pragma unroll
    for (int j = 0; j < TN; ++j) acc[i][j] = 0.f;

  for (int k0 = 0; k0 < K; k0 += BK) {
    for (int idx = tid; idx < BM * BK / 4; idx += 320) {
      int r = idx / (BK / 4);
      int c4 = idx % (BK / 4);
      int row = row0 + r;
      float4 v = (row < M) ? *(const float4*)(A + (size_t)row * K + k0 + c4 * 4)
                           : make_float4(0.f, 0.f, 0.f, 0.f);
      As[c4 * 4 + 0][r] = v.x;
      As[c4 * 4 + 1][r] = v.y;
      As[c4 * 4 + 2][r] = v.z;
      As[c4 * 4 + 3][r] = v.w;
    }
    {
      int r = tid / 10;
      int c4 = tid % 10;
      *(float4*)(&Bs[r][c4 * 4]) =
          *(const float4*)(B + (size_t)(k0 + r) * N + c4 * 4);
    }
    __syncthreads();
#pragma unroll
    for (int k = 0; k < BK; ++k) {
      float4 a0 = *(const float4*)(&As[k][ty * TM]);
      float4 b0 = *(const float4*)(&Bs[k][tx * TN]);
      float a[TM] = {a0.x, a0.y, a0.z, a0.w};
      float b[TN] = {b0.x, b0.y, b0.z, b0.w};
#pragma unroll
      for (int i = 0; i < TM; ++i)
#pragma unroll
        for (int j = 0; j < TN; ++j) acc[i][j] += a[i] * b[j];
    }
    __syncthreads();
  }

#pragma unroll
  for (int i = 0; i < TM; ++i) {
    int row = row0 + ty * TM + i;
    if (row >= M) continue;
    float rs = rowscale[row];
    float4 v = make_float4(acc[i][0] * rs, acc[i][1] * rs,
                           acc[i][2] * rs, acc[i][3] * rs);
    *(float4*)(C + (size_t)row * N + tx * TN) = v;
  }
}

// ---------------------------------------------------------------------------
// Pass 9: layer-2 aggregation at dim 40 + bias + log_softmax.
// ---------------------------------------------------------------------------
__global__ __launch_bounds__(256) void agg2_softmax_kernel(
    const float* __restrict__ t, const int* __restrict__ row_ptr,
    const int* __restrict__ csr_src, const float* __restrict__ norm_dst,
    const float* __restrict__ b2, float* __restrict__ out) {
  int wid = (blockIdx.x * 256 + threadIdx.x) >> 6;
  if (wid >= N_NODES) return;
  int lane = threadIdx.x & 63;
  int g = lane >> 4;
  int l16 = lane & 15;
  bool act = l16 < 10;
  int beg = row_ptr[wid], end = row_ptr[wid + 1];
  float4 acc = make_float4(0.f, 0.f, 0.f, 0.f);
  for (int e = beg + g; e < end; e += 4) {
    int s = csr_src[e];
    if (act) {
      float4 f = *(const float4*)(t + (size_t)s * F_OUT + (l16 << 2));
      acc.x += f.x; acc.y += f.y; acc.z += f.z; acc.w += f.w;
    }
  }
#pragma unroll
  for (int off = 16; off <= 32; off <<= 1) {
    acc.x += __shfl_xor(acc.x, off);
    acc.y += __shfl_xor(acc.y, off);
    acc.z += __shfl_xor(acc.z, off);
    acc.w += __shfl_xor(acc.w, off);
  }
  float nd = norm_dst[wid];
  float4 v;
  if (act) {
    float4 bv = *(const float4*)(b2 + (l16 << 2));
    v = make_float4(acc.x * nd + bv.x, acc.y * nd + bv.y,
                    acc.z * nd + bv.z, acc.w * nd + bv.w);
  } else {
    v = make_float4(-INFINITY, -INFINITY, -INFINITY, -INFINITY);
  }
  float m = fmaxf(fmaxf(v.x, v.y), fmaxf(v.z, v.w));
#pragma unroll
  for (int off = 1; off <= 8; off <<= 1) m = fmaxf(m, __shfl_xor(m, off));
  float ex = act ? (expf(v.x - m) + expf(v.y - m) + expf(v.z - m) + expf(v.w - m)) : 0.f;
#pragma unroll
  for (int off = 1; off <= 8; off <<= 1) ex += __shfl_xor(ex, off);
  float ls = logf(ex);
  if (g == 0 && act) {
    float4 r = make_float4(v.x - m - ls, v.y - m - ls, v.z - m - ls, v.w - m - ls);
    *(float4*)(out + (size_t)wid * F_OUT + (l16 << 2)) = r;
  }
}

// ---------------------------------------------------------------------------
extern "C" void kernel_launch(void* const* d_in, const int* in_sizes, int n_in,
                              void* d_out, int out_size, void* d_ws, size_t ws_size,
                              hipStream_t stream) {
  const float* feat = (const float*)d_in[0];
  const float* W1   = (const float*)d_in[1];
  const float* b1   = (const float*)d_in[2];
  const float* W2   = (const float*)d_in[3];
  const float* b2   = (const float*)d_in[4];
  const int*   src  = (const int*)d_in[5];
  const int*   dst  = (const int*)d_in[6];
  float* out = (float*)d_out;

  char* p = (char*)d_ws;
  auto alloc = [&](size_t bytes) {
    char* r = p;
    p += (bytes + 255) & ~(size_t)255;
    return r;
  };
  int*   degc_out = (int*)alloc((size_t)NCOPY * SREP * 4);  // 1.6 MB
  int*   degc_in  = (int*)alloc((size_t)NCOPY * SREP * 4);  // 1.6 MB
  int*   cur      = (int*)alloc((size_t)NCOPY * SREP * 4);  // 1.6 MB (no init needed)
  int*   deg_in_tot = (int*)alloc((size_t)N_NODES * 4);
  int*   bsum     = (int*)alloc((size_t)NB * 4);
  int*   row_ptr  = (int*)alloc((size_t)(N_NODES + 1) * 4);
  int*   csr_src  = (int*)alloc((size_t)N_EDGES * 4);
  float* norm_src = (float*)alloc((size_t)N_NODES * 4);
  float* norm_dst = (float*)alloc((size_t)N_NODES * 4);
  float* t        = (float*)alloc((size_t)N_NODES * F_OUT * 4);
  float* xs       = (float*)alloc((size_t)N_NODES * F_HID * 4);  // h overlays xs
  float* h        = xs;
  float* agg1     = (float*)alloc((size_t)N_NODES * F_IN * 4);

  // zero both replicated histograms (contiguous span, pointer-derived so the
  // 256B alloc padding is covered)
  size_t zero_bytes = (size_t)((char*)cur - (char*)degc_out);
  hipMemsetAsync(degc_out, 0, zero_bytes, stream);

  degree_kernel<<<(N_EDGES + 255) / 256, 256, 0, stream>>>(src, dst, degc_out, degc_in);
  reduce_kernel<<<NB, 256, 0, stream>>>(degc_out, degc_in, deg_in_tot, norm_src, norm_dst);
  block_sum_kernel<<<NB, 256, 0, stream>>>(deg_in_tot, bsum);
  scan_bsum_kernel<<<1, 256, 0, stream>>>(bsum);
  finalize_kernel<<<NB, 256, 0, stream>>>(deg_in_tot, degc_in, bsum, row_ptr, cur);
  scatter_kernel<<<(N_EDGES + 255) / 256, 256, 0, stream>>>(src, dst, cur, csr_src);
  prescale_kernel<<<N_NODES * (F_IN / 4) / 256, 256, 0, stream>>>(feat, norm_src, xs);
  agg1_kernel<<<(N_NODES * 64) / 256 + 1, 256, 0, stream>>>(xs, row_ptr, csr_src,
                                                            norm_dst, agg1);
  gemm1_kernel<<<dim3((N_NODES + 127) / 128, F_HID / 64), 256, 0, stream>>>(
      agg1, W1, b1, h, N_NODES);
  gemm2_kernel<<<(N_NODES + 127) / 128, 320, 0, stream>>>(h, W2, norm_src, t, N_NODES);
  agg2_softmax_kernel<<<(N_NODES * 64) / 256 + 1, 256, 0, stream>>>(
      t, row_ptr, csr_src, norm_dst, b2, out);
}